// Round 3
// baseline (518.389 us; speedup 1.0000x reference)
//
#include <hip/hip_runtime.h>

#define NSRC 100000
#define NTGT 50000
#define NE   600000
#define CH   128
#define NREL 7
#define NTYP 4
#define NP   (NREL * NTGT)          // 350000 (rel,dst) pairs
#define NB   ((NP + 1023) / 1024)   // scan blocks (342)
#define NBLK ((NTGT + 31) / 32)     // 1563 dst tiles (32 rows per block, 8 per wave)

typedef __attribute__((ext_vector_type(4))) float f32x4;
typedef __attribute__((ext_vector_type(8))) short bf16x8;
typedef unsigned int uint;
typedef unsigned short ushort;

static constexpr long long NXB4 = (long long)NSRC * CH / 4;
static constexpr long long NXT4 = (long long)NTGT * CH / 4;
static constexpr long long NWR4 = (long long)NREL * CH * CH / 4;
static constexpr long long NWT4 = (long long)NTYP * CH * CH / 4;
static constexpr int CONVB  = (int)((NXB4 + NXT4 + NWR4 + NWT4 + 255) / 256);
static constexpr int COUNTB = (NE + 255) / 256;

// ---- workspace layout ----
static constexpr size_t A256(size_t x) { return (x + 255) & ~(size_t)255; }
static constexpr size_t CNT_O   = 0;                                   // int[NP] (memset 0)
static constexpr size_t BSE_O   = A256(CNT_O + (size_t)NP * 4);        // int[NB]
static constexpr size_t EOFF_O  = A256(BSE_O + (size_t)NB * 4);        // int[NP+1]
static constexpr size_t CUR_O   = A256(EOFF_O + (size_t)(NP + 1) * 4); // int[NP]
static constexpr size_t SEDGE_O = A256(CUR_O + (size_t)NP * 4);        // int[NE]
static constexpr size_t WB_O    = A256(SEDGE_O + (size_t)NE * 4);      // bf16[11*CH*CH]
static constexpr size_t XB_O    = A256(WB_O + (size_t)(NREL + NTYP) * CH * CH * 2);
static constexpr size_t XTB_O   = A256(XB_O + (size_t)NSRC * CH * 2);  // bf16[NTGT*CH]

__device__ __forceinline__ uint bfpack(float a, float b) {
  uint ua = __float_as_uint(a); ua = (ua + 0x7fff + ((ua >> 16) & 1)) >> 16;
  uint ub = __float_as_uint(b); ub = (ub + 0x7fff + ((ub >> 16) & 1)) >> 16;
  return ua | (ub << 16);
}
__device__ __forceinline__ ushort f2b(float x) {
  uint u = __float_as_uint(x);
  return (ushort)((u + 0x7fff + ((u >> 16) & 1)) >> 16);
}
__device__ __forceinline__ float bl(uint u) { return __uint_as_float(u << 16); }
__device__ __forceinline__ float bh(uint u) { return __uint_as_float(u & 0xffff0000u); }

__device__ __forceinline__ void add8(float* a, uint4 u) {
  a[0] += bl(u.x); a[1] += bh(u.x);
  a[2] += bl(u.y); a[3] += bh(u.y);
  a[4] += bl(u.z); a[5] += bh(u.z);
  a[6] += bl(u.w); a[7] += bh(u.w);
}

// ---- count edges per (rel,dst) pair ----
__global__ __launch_bounds__(256) void k_count(const int* __restrict__ edst,
                                               const int* __restrict__ etyp,
                                               int* __restrict__ cnt) {
  int i = blockIdx.x * 256 + threadIdx.x;
  if (i < NE) atomicAdd(&cnt[etyp[i] * NTGT + edst[i]], 1);
}

__global__ __launch_bounds__(256) void k_s1(const int* __restrict__ cnt,
                                            int* __restrict__ bsE) {
  __shared__ int sE[256];
  int t = threadIdx.x, p0 = blockIdx.x * 1024 + t * 4;
  int e = 0;
#pragma unroll
  for (int j = 0; j < 4; ++j) {
    int p = p0 + j;
    if (p < NP) e += cnt[p];
  }
  sE[t] = e; __syncthreads();
  for (int s = 128; s > 0; s >>= 1) {
    if (t < s) sE[t] += sE[t + s];
    __syncthreads();
  }
  if (t == 0) bsE[blockIdx.x] = sE[0];
}

// fused s2+s3: each block re-scans the 342 block sums, then scans its own chunk
__global__ __launch_bounds__(512) void k_s23(const int* __restrict__ cnt,
                                             const int* __restrict__ bsE,
                                             int* __restrict__ eoff,
                                             int* __restrict__ cur) {
  __shared__ int sE[512];
  __shared__ int sBase;
  int t = threadIdx.x;
  int e = (t < NB) ? bsE[t] : 0;
  sE[t] = e; __syncthreads();
  for (int s = 1; s < 512; s <<= 1) {
    int a = 0; if (t >= s) a = sE[t - s];
    __syncthreads();
    sE[t] += a;
    __syncthreads();
  }
  if (t == blockIdx.x) sBase = sE[t] - e;   // exclusive prefix for this block
  __syncthreads();
  int base0 = sBase;
  int p0 = blockIdx.x * 1024 + t * 2;
  int c0 = (p0 < NP) ? cnt[p0] : 0;
  int c1 = (p0 + 1 < NP) ? cnt[p0 + 1] : 0;
  int e2 = c0 + c1;
  sE[t] = e2; __syncthreads();
  for (int s = 1; s < 512; s <<= 1) {
    int a = 0; if (t >= s) a = sE[t - s];
    __syncthreads();
    sE[t] += a;
    __syncthreads();
  }
  int baseE = base0 + sE[t] - e2;
  if (p0 < NP)     { eoff[p0] = baseE;     cur[p0] = baseE; }
  if (p0 + 1 < NP) { eoff[p0 + 1] = baseE + c0; cur[p0 + 1] = baseE + c0; }
  if (p0 + 1 == NP - 1) eoff[NP] = baseE + c0 + c1;   // sentinel = NE
}

// ---- fused: edge sort (bucket scatter) + fp32->bf16 conversion ----
__global__ __launch_bounds__(256) void k_esconv(
    const int* __restrict__ esrc, const int* __restrict__ edst,
    const int* __restrict__ etyp, int* __restrict__ cur, int* __restrict__ sedge,
    const float* __restrict__ xsrc, const float* __restrict__ xt,
    const float* __restrict__ relw, const float* __restrict__ rootw,
    ushort* __restrict__ xb, ushort* __restrict__ xtb, ushort* __restrict__ wb) {
  int bx = blockIdx.x;
  if (bx < COUNTB) {
    int i = bx * 256 + threadIdx.x;
    if (i < NE) {
      int p = etyp[i] * NTGT + edst[i];
      int pos = atomicAdd(&cur[p], 1);
      sedge[pos] = esrc[i];
    }
    return;
  }
  bx -= COUNTB;
  long long i4 = (long long)bx * 256 + threadIdx.x;
  const float* src; ushort* dst; long long off;
  if (i4 < NXB4) { src = xsrc; dst = xb; off = i4; }
  else if (i4 < NXB4 + NXT4) { src = xt; dst = xtb; off = i4 - NXB4; }
  else if (i4 < NXB4 + NXT4 + NWR4) { src = relw; dst = wb; off = i4 - NXB4 - NXT4; }
  else if (i4 < NXB4 + NXT4 + NWR4 + NWT4) {
    src = rootw; dst = wb + (size_t)NREL * CH * CH; off = i4 - NXB4 - NXT4 - NWR4;
  } else return;
  float4 v = *(const float4*)(src + off * 4);
  uint lo = (uint)f2b(v.x) | ((uint)f2b(v.y) << 16);
  uint hi = (uint)f2b(v.z) | ((uint)f2b(v.w) << 16);
  uint2 o = make_uint2(lo, hi);
  *(uint2*)(dst + off * 4) = o;
}

__device__ __forceinline__ void mfma_acc(const ushort* strip, const ushort* W,
                                         int m, int quad, f32x4* acc) {
  bf16x8 aF[4];
#pragma unroll
  for (int ks = 0; ks < 4; ++ks) {
    int c = ks * 4 + quad;
    aF[ks] = *(const bf16x8*)&strip[(m * 16 + (c ^ m)) << 3];
  }
#pragma unroll
  for (int ct = 0; ct < 8; ++ct) {
    int n = ct * 16 + m;
#pragma unroll
    for (int ks = 0; ks < 4; ++ks) {
      bf16x8 bF = *(const bf16x8*)(W + (size_t)n * CH + ks * 32 + quad * 8);
      acc[ct] = __builtin_amdgcn_mfma_f32_16x16x32_bf16(aF[ks], bF, acc[ct], 0, 0, 0);
    }
  }
}

// dst-major mega kernel, 8 dst rows per wave (rows q and q+4 per 16-lane quarter):
//  - edge indices loaded lane-parallel (1 coalesced load per row per 16-edge chunk)
//  - per-edge src extracted via register __shfl (no memory wait)
//  - row gather: lane t loads uint4 (16 lanes x 16B = 256B row), 4 rows/instr
//  - accumulation entirely in registers (no LDS RMW), software-pipelined depth 2
//  - strips are wave-private LDS; no __syncthreads anywhere
__global__ __launch_bounds__(256, 4) void k_mega(const ushort* __restrict__ xb,
    const ushort* __restrict__ xtb, const ushort* __restrict__ wb,
    const int* __restrict__ eoff, const int* __restrict__ sedge,
    const int* __restrict__ ntyp, const float* __restrict__ rootb,
    float* __restrict__ out) {
  __shared__ ushort As[4 * 16 * CH];    // 16 KB, 4 KB per wave
  int wv = threadIdx.x >> 6, ln = threadIdx.x & 63;
  ushort* strip = As + wv * (16 * CH);
  int q = ln >> 4;        // quarter 0..3 : handles rows q and q+4
  int t = ln & 15;        // channel group within row (channels t*8 .. t*8+8)
  int m = ln & 15, quad = ln >> 4;   // mfma naming

  int dstbase = blockIdx.x * 32 + wv * 8;
  if (dstbase >= NTGT) return;       // safe: no block-wide syncs in this kernel

  f32x4 acc[8];
#pragma unroll
  for (int ct = 0; ct < 8; ++ct) acc[ct] = (f32x4){0.f, 0.f, 0.f, 0.f};

  // ---- 7 relation phases ----
  for (int rel = 0; rel < NREL; ++rel) {
    int p0 = rel * NTGT + dstbase;
    int ev = 0;
    if (ln < 9) ev = eoff[p0 + ln];          // 9 consecutive offsets
    int eA0 = __shfl(ev, q),     eA1 = __shfl(ev, q + 1);
    int eB0 = __shfl(ev, q + 4), eB1 = __shfl(ev, q + 5);
    int etot = __shfl(ev, 8) - __shfl(ev, 0);  // uniform
    if (etot == 0) continue;                   // no edges for these 8 rows
    int na = eA1 - eA0, nb = eB1 - eB0;

    float accA[8], accB[8];
#pragma unroll
    for (int c = 0; c < 8; ++c) { accA[c] = 0.f; accB[c] = 0.f; }

    // wave-uniform max row count
    int u = max(na, nb);
    u = max(u, __shfl_xor(u, 16));
    u = max(u, __shfl_xor(u, 32));

    for (int base = 0; base < u; base += 16) {
      int ca = min(na - base, 16); if (ca < 0) ca = 0;
      int cb = min(nb - base, 16); if (cb < 0) cb = 0;
      // lane-parallel index load: one coalesced load per row per chunk
      int sidxA = (t < ca) ? sedge[eA0 + base + t] : 0;
      int sidxB = (t < cb) ? sedge[eB0 + base + t] : 0;
      int cmax = u - base; if (cmax > 16) cmax = 16;   // uniform trip

      // depth-2 software pipeline over edges
      uint4 va = {0, 0, 0, 0}, vb = {0, 0, 0, 0};
      bool la = (0 < ca), lb = (0 < cb);
      if (la) {
        int s = __shfl(sidxA, (q << 4));
        va = *(const uint4*)(xb + (size_t)s * CH + (t << 3));
      }
      if (lb) {
        int s = __shfl(sidxB, (q << 4));
        vb = *(const uint4*)(xb + (size_t)s * CH + (t << 3));
      }
      for (int j = 0; j < cmax; ++j) {
        uint4 ua = va, ub = vb;
        bool pa = la, pb = lb;
        la = (j + 1 < ca); lb = (j + 1 < cb);
        if (la) {
          int s = __shfl(sidxA, (q << 4) + j + 1);
          va = *(const uint4*)(xb + (size_t)s * CH + (t << 3));
        }
        if (lb) {
          int s = __shfl(sidxB, (q << 4) + j + 1);
          vb = *(const uint4*)(xb + (size_t)s * CH + (t << 3));
        }
        if (pa) add8(accA, ua);
        if (pb) add8(accB, ub);
      }
    }

    // mean + bf16 pack -> wave-private swizzled strip (rows q and q+4)
    float invA = (na > 0) ? __builtin_amdgcn_rcpf((float)na) : 0.f;
    float invB = (nb > 0) ? __builtin_amdgcn_rcpf((float)nb) : 0.f;
    uint4 wA, wB;
    wA.x = bfpack(accA[0] * invA, accA[1] * invA);
    wA.y = bfpack(accA[2] * invA, accA[3] * invA);
    wA.z = bfpack(accA[4] * invA, accA[5] * invA);
    wA.w = bfpack(accA[6] * invA, accA[7] * invA);
    wB.x = bfpack(accB[0] * invB, accB[1] * invB);
    wB.y = bfpack(accB[2] * invB, accB[3] * invB);
    wB.z = bfpack(accB[4] * invB, accB[5] * invB);
    wB.w = bfpack(accB[6] * invB, accB[7] * invB);
    *(uint4*)&strip[(q * 16 + (t ^ q)) << 3] = wA;
    *(uint4*)&strip[((q + 4) * 16 + (t ^ (q + 4))) << 3] = wB;
    // rows 8..15 of strip are never written: their MFMA output rows are discarded

    mfma_acc(strip, wb + (size_t)rel * CH * CH, m, quad, acc);
  }

  // ---- 4 root-type phases ----
  int dA = dstbase + q, dB = dstbase + q + 4;
  uint4 xrA = *(const uint4*)(xtb + (size_t)dA * CH + (t << 3));
  uint4 xrB = *(const uint4*)(xtb + (size_t)dB * CH + (t << 3));
  int ntA = ntyp[dA], ntB = ntyp[dB];
  const uint4 z4 = {0, 0, 0, 0};
  for (int ty = 0; ty < NTYP; ++ty) {
    uint4 wA = (ntA == ty) ? xrA : z4;
    uint4 wB = (ntB == ty) ? xrB : z4;
    *(uint4*)&strip[(q * 16 + (t ^ q)) << 3] = wA;
    *(uint4*)&strip[((q + 4) * 16 + (t ^ (q + 4))) << 3] = wB;
    mfma_acc(strip, wb + (size_t)(NREL + ty) * CH * CH, m, quad, acc);
  }

  // ---- epilogue: add bias, plain coalesced store (rows 0..7 only) ----
#pragma unroll
  for (int reg = 0; reg < 4; ++reg) {
    int row = quad * 4 + reg;
    if (row < 8) {
      int dst = dstbase + row;
      int tt = ntyp[dst];
      const float* rb = rootb + (size_t)tt * CH;
#pragma unroll
      for (int ct = 0; ct < 8; ++ct) {
        int col = ct * 16 + m;
        out[(size_t)dst * CH + col] = acc[ct][reg] + rb[col];
      }
    }
  }
}

extern "C" void kernel_launch(void* const* d_in, const int* in_sizes, int n_in,
                              void* d_out, int out_size, void* d_ws, size_t ws_size,
                              hipStream_t stream) {
  (void)in_sizes; (void)n_in; (void)out_size; (void)ws_size;
  const float* xsrc  = (const float*)d_in[0];
  const float* xt    = (const float*)d_in[1];
  const float* relw  = (const float*)d_in[2];
  const float* rootw = (const float*)d_in[3];
  const float* rootb = (const float*)d_in[4];
  const int* esrc = (const int*)d_in[5];
  const int* edst = (const int*)d_in[6];
  const int* etyp = (const int*)d_in[7];
  const int* ntyp = (const int*)d_in[8];
  float* out = (float*)d_out;

  char* ws = (char*)d_ws;
  int*   cnt    = (int*)(ws + CNT_O);
  int*   bsE    = (int*)(ws + BSE_O);
  int*   eoff   = (int*)(ws + EOFF_O);
  int*   cur    = (int*)(ws + CUR_O);
  int*   sedge  = (int*)(ws + SEDGE_O);
  ushort* wb    = (ushort*)(ws + WB_O);
  ushort* xb    = (ushort*)(ws + XB_O);
  ushort* xtb   = (ushort*)(ws + XTB_O);

  hipMemsetAsync(cnt, 0, (size_t)NP * 4, stream);
  k_count<<<dim3(COUNTB), dim3(256), 0, stream>>>(edst, etyp, cnt);
  k_s1<<<dim3(NB), dim3(256), 0, stream>>>(cnt, bsE);
  k_s23<<<dim3(NB), dim3(512), 0, stream>>>(cnt, bsE, eoff, cur);
  k_esconv<<<dim3(COUNTB + CONVB), dim3(256), 0, stream>>>(
      esrc, edst, etyp, cur, sedge, xsrc, xt, relw, rootw, xb, xtb, wb);
  k_mega<<<dim3(NBLK), dim3(256), 0, stream>>>(
      xb, xtb, wb, eoff, sedge, ntyp, rootb, out);
}

// Round 4
// 403.431 us; speedup vs baseline: 1.2849x; 1.2849x over previous
//
#include <hip/hip_runtime.h>

#define NSRC 100000
#define NTGT 50000
#define NE   600000
#define CH   128
#define NREL 7
#define NTYP 4
#define NP   (NREL * NTGT)          // 350000 (rel,dst) pairs
#define NB   ((NP + 1023) / 1024)   // scan blocks (342)
#define NBLK (NTGT / 16)            // 3125 one-wave blocks, 16 dst rows each

typedef __attribute__((ext_vector_type(4))) float f32x4;
typedef __attribute__((ext_vector_type(8))) short bf16x8;
typedef unsigned int uint;
typedef unsigned short ushort;

static constexpr long long NXB4 = (long long)NSRC * CH / 4;
static constexpr long long NXT4 = (long long)NTGT * CH / 4;
static constexpr long long NWR4 = (long long)NREL * CH * CH / 4;
static constexpr long long NWT4 = (long long)NTYP * CH * CH / 4;
static constexpr int CONVB  = (int)((NXB4 + NXT4 + NWR4 + NWT4 + 255) / 256);
static constexpr int COUNTB = (NE + 255) / 256;

// ---- workspace layout ----
static constexpr size_t A256(size_t x) { return (x + 255) & ~(size_t)255; }
static constexpr size_t CNT_O   = 0;                                   // int[NP] (memset 0)
static constexpr size_t BSE_O   = A256(CNT_O + (size_t)NP * 4);        // int[NB]
static constexpr size_t EOFF_O  = A256(BSE_O + (size_t)NB * 4);        // int[NP+1]
static constexpr size_t CUR_O   = A256(EOFF_O + (size_t)(NP + 1) * 4); // int[NP]
static constexpr size_t SEDGE_O = A256(CUR_O + (size_t)NP * 4);        // int[NE]
static constexpr size_t WB_O    = A256(SEDGE_O + (size_t)NE * 4);      // bf16[11*CH*CH]
static constexpr size_t XB_O    = A256(WB_O + (size_t)(NREL + NTYP) * CH * CH * 2);
static constexpr size_t XTB_O   = A256(XB_O + (size_t)NSRC * CH * 2);  // bf16[NTGT*CH]

#define GLOAD_LDS(gp, lp) __builtin_amdgcn_global_load_lds( \
    (const __attribute__((address_space(1))) void*)(gp), \
    (__attribute__((address_space(3))) void*)(lp), 16, 0, 0)
#define FENCE_VM()   asm volatile("s_waitcnt vmcnt(0)" ::: "memory")
#define FENCE_FULL() asm volatile("s_waitcnt vmcnt(0) lgkmcnt(0)" ::: "memory")

__device__ __forceinline__ uint bfpack(float a, float b) {
  uint ua = __float_as_uint(a); ua = (ua + 0x7fff + ((ua >> 16) & 1)) >> 16;
  uint ub = __float_as_uint(b); ub = (ub + 0x7fff + ((ub >> 16) & 1)) >> 16;
  return ua | (ub << 16);
}
__device__ __forceinline__ ushort f2b(float x) {
  uint u = __float_as_uint(x);
  return (ushort)((u + 0x7fff + ((u >> 16) & 1)) >> 16);
}
__device__ __forceinline__ float bl(uint u) { return __uint_as_float(u << 16); }
__device__ __forceinline__ float bh(uint u) { return __uint_as_float(u & 0xffff0000u); }

// ---- count edges per (rel,dst) pair ----
__global__ __launch_bounds__(256) void k_count(const int* __restrict__ edst,
                                               const int* __restrict__ etyp,
                                               int* __restrict__ cnt) {
  int i = blockIdx.x * 256 + threadIdx.x;
  if (i < NE) atomicAdd(&cnt[etyp[i] * NTGT + edst[i]], 1);
}

__global__ __launch_bounds__(256) void k_s1(const int* __restrict__ cnt,
                                            int* __restrict__ bsE) {
  __shared__ int sE[256];
  int t = threadIdx.x, p0 = blockIdx.x * 1024 + t * 4;
  int e = 0;
#pragma unroll
  for (int j = 0; j < 4; ++j) {
    int p = p0 + j;
    if (p < NP) e += cnt[p];
  }
  sE[t] = e; __syncthreads();
  for (int s = 128; s > 0; s >>= 1) {
    if (t < s) sE[t] += sE[t + s];
    __syncthreads();
  }
  if (t == 0) bsE[blockIdx.x] = sE[0];
}

// fused s2+s3: each block re-scans the 342 block sums, then scans its own chunk
__global__ __launch_bounds__(512) void k_s23(const int* __restrict__ cnt,
                                             const int* __restrict__ bsE,
                                             int* __restrict__ eoff,
                                             int* __restrict__ cur) {
  __shared__ int sE[512];
  __shared__ int sBase;
  int t = threadIdx.x;
  int e = (t < NB) ? bsE[t] : 0;
  sE[t] = e; __syncthreads();
  for (int s = 1; s < 512; s <<= 1) {
    int a = 0; if (t >= s) a = sE[t - s];
    __syncthreads();
    sE[t] += a;
    __syncthreads();
  }
  if (t == blockIdx.x) sBase = sE[t] - e;   // exclusive prefix for this block
  __syncthreads();
  int base0 = sBase;
  int p0 = blockIdx.x * 1024 + t * 2;
  int c0 = (p0 < NP) ? cnt[p0] : 0;
  int c1 = (p0 + 1 < NP) ? cnt[p0 + 1] : 0;
  int e2 = c0 + c1;
  sE[t] = e2; __syncthreads();
  for (int s = 1; s < 512; s <<= 1) {
    int a = 0; if (t >= s) a = sE[t - s];
    __syncthreads();
    sE[t] += a;
    __syncthreads();
  }
  int baseE = base0 + sE[t] - e2;
  if (p0 < NP)     { eoff[p0] = baseE;          cur[p0] = baseE; }
  if (p0 + 1 < NP) { eoff[p0 + 1] = baseE + c0; cur[p0 + 1] = baseE + c0; }
  if (p0 + 1 == NP - 1) eoff[NP] = baseE + c0 + c1;   // sentinel = NE
}

// ---- fused: edge sort (bucket scatter) + fp32->bf16 conversion ----
__global__ __launch_bounds__(256) void k_esconv(
    const int* __restrict__ esrc, const int* __restrict__ edst,
    const int* __restrict__ etyp, int* __restrict__ cur, int* __restrict__ sedge,
    const float* __restrict__ xsrc, const float* __restrict__ xt,
    const float* __restrict__ relw, const float* __restrict__ rootw,
    ushort* __restrict__ xb, ushort* __restrict__ xtb, ushort* __restrict__ wb) {
  int bx = blockIdx.x;
  if (bx < COUNTB) {
    int i = bx * 256 + threadIdx.x;
    if (i < NE) {
      int p = etyp[i] * NTGT + edst[i];
      int pos = atomicAdd(&cur[p], 1);
      sedge[pos] = esrc[i];
    }
    return;
  }
  bx -= COUNTB;
  long long i4 = (long long)bx * 256 + threadIdx.x;
  const float* src; ushort* dst; long long off;
  if (i4 < NXB4) { src = xsrc; dst = xb; off = i4; }
  else if (i4 < NXB4 + NXT4) { src = xt; dst = xtb; off = i4 - NXB4; }
  else if (i4 < NXB4 + NXT4 + NWR4) { src = relw; dst = wb; off = i4 - NXB4 - NXT4; }
  else if (i4 < NXB4 + NXT4 + NWR4 + NWT4) {
    src = rootw; dst = wb + (size_t)NREL * CH * CH; off = i4 - NXB4 - NXT4 - NWR4;
  } else return;
  float4 v = *(const float4*)(src + off * 4);
  uint lo = (uint)f2b(v.x) | ((uint)f2b(v.y) << 16);
  uint hi = (uint)f2b(v.z) | ((uint)f2b(v.w) << 16);
  uint2 o = make_uint2(lo, hi);
  *(uint2*)(dst + off * 4) = o;
}

__device__ __forceinline__ void mfma_acc(const ushort* strip, const ushort* W,
                                         int m, int quad, f32x4* acc) {
  bf16x8 aF[4];
#pragma unroll
  for (int ks = 0; ks < 4; ++ks) {
    int c = ks * 4 + quad;
    aF[ks] = *(const bf16x8*)&strip[(m * 16 + (c ^ m)) << 3];
  }
#pragma unroll
  for (int ct = 0; ct < 8; ++ct) {
    int n = ct * 16 + m;
#pragma unroll
    for (int ks = 0; ks < 4; ++ks) {
      bf16x8 bF = *(const bf16x8*)(W + (size_t)n * CH + ks * 32 + quad * 8);
      acc[ct] = __builtin_amdgcn_mfma_f32_16x16x32_bf16(aF[ks], bF, acc[ct], 0, 0, 0);
    }
  }
}

// One-wave mega kernel: 16 dst rows per block.
//  - All 7 relations' offset windows + 16 root rows prefetched at start.
//  - Per 16-edge chunk: 4 independent index loads -> fence -> 4 independent
//    global_load_lds (each stages 4 edges' 256B rows, per-lane global scatter,
//    zero VGPR round-trip) -> fence -> LDS-read accumulate into statically
//    indexed register accumulators (row bounds are readlane scalars).
//  - Mean+pack -> swizzled strip (overlaid on staging buffer) -> MFMA.
//  - Root: 4 one-hot phases from prefetched registers. Bias folded, plain store.
__global__ __launch_bounds__(64) void k_mega(const ushort* __restrict__ xb,
    const ushort* __restrict__ xtb, const ushort* __restrict__ wb,
    const int* __restrict__ eoff, const int* __restrict__ sedge,
    const int* __restrict__ ntyp, const float* __restrict__ rootb,
    float* __restrict__ out) {
  __shared__ ushort As[16 * CH];        // 4 KB: staging (16 x 256B) / strip overlay
  int ln = threadIdx.x;
  int m = ln & 15, quad = ln >> 4;
  int dstbase = blockIdx.x * 16;

  // prefetch: 7 relation offset windows (17 values each), root rows, row types
  int lc = min(ln, 16);
  int evr[NREL];
#pragma unroll
  for (int r = 0; r < NREL; ++r)
    evr[r] = eoff[r * NTGT + dstbase + lc];
  int nv = ntyp[dstbase + min(ln, 15)];
  uint xr[16];
#pragma unroll
  for (int i = 0; i < 16; ++i)
    xr[i] = *(const uint*)(xtb + (size_t)(dstbase + i) * CH + (ln << 1));

  f32x4 acc[8];
#pragma unroll
  for (int ct = 0; ct < 8; ++ct) acc[ct] = (f32x4){0.f, 0.f, 0.f, 0.f};

  // ---- 7 relation phases ----
#pragma unroll
  for (int rel = 0; rel < NREL; ++rel) {
    int ev = evr[rel];
    int e0 = __builtin_amdgcn_readlane(ev, 0);
    int e1 = __builtin_amdgcn_readlane(ev, 16);
    if (e1 <= e0) continue;             // whole 16-row group empty for this rel

    float aRx[16], aRy[16];
#pragma unroll
    for (int i = 0; i < 16; ++i) { aRx[i] = 0.f; aRy[i] = 0.f; }

    for (int cb = e0; cb < e1; cb += 16) {
      int nc = e1 - cb; if (nc > 16) nc = 16;
      int ng = (nc + 3) >> 2;
      // 1) independent index loads (4 distinct addrs each, 16x duplicated)
      uint ai[4];
      int esl = cb + (ln >> 4);
#pragma unroll
      for (int g = 0; g < 4; ++g) {
        if (g < ng) {
          int e = esl + g * 4;
          if (e > e1 - 1) e = e1 - 1;   // clamp: pads stage with dup row, never read
          ai[g] = (uint)sedge[e];
        }
      }
      FENCE_FULL();                     // idx ready; prior LDS reads drained
      // 2) independent DMA stages: 4 edges' rows per instruction, LDS linear
#pragma unroll
      for (int g = 0; g < 4; ++g) {
        if (g < ng) {
          const ushort* gp = xb + (size_t)ai[g] * CH + ((ln & 15) << 3);
          GLOAD_LDS(gp, &As[g << 9]);
        }
      }
      FENCE_VM();                       // staged data landed
      // 3) accumulate rows (bounds are wave-uniform scalars; static reg index)
#pragma unroll
      for (int i = 0; i < 16; ++i) {
        int lo = __builtin_amdgcn_readlane(ev, i);
        int hi = __builtin_amdgcn_readlane(ev, i + 1);
        if (lo < cb) lo = cb;
        int ce = cb + nc; if (hi > ce) hi = ce;
        for (int e = lo; e < hi; ++e) {
          uint u = *(const uint*)&As[((e - cb) << 7) + (ln << 1)];
          aRx[i] += bl(u);
          aRy[i] += bh(u);
        }
      }
    }

    // mean + bf16 pack -> swizzled strip (overlays staging buffer)
#pragma unroll
    for (int i = 0; i < 16; ++i) {
      int n = __builtin_amdgcn_readlane(ev, i + 1) - __builtin_amdgcn_readlane(ev, i);
      float inv = (n > 0) ? __builtin_amdgcn_rcpf((float)n) : 0.f;
      uint w = bfpack(aRx[i] * inv, aRy[i] * inv);
      int c = ln >> 2;
      *(uint*)&As[((i * 16 + (c ^ i)) << 3) + ((ln & 3) << 1)] = w;
    }
    mfma_acc(As, wb + (size_t)rel * CH * CH, m, quad, acc);
  }

  // ---- 4 root-type phases (one-hot from prefetched registers) ----
#pragma unroll
  for (int ty = 0; ty < NTYP; ++ty) {
#pragma unroll
    for (int i = 0; i < 16; ++i) {
      int nti = __builtin_amdgcn_readlane(nv, i);
      uint w = (nti == ty) ? xr[i] : 0u;
      int c = ln >> 2;
      *(uint*)&As[((i * 16 + (c ^ i)) << 3) + ((ln & 3) << 1)] = w;
    }
    mfma_acc(As, wb + (size_t)(NREL + ty) * CH * CH, m, quad, acc);
  }

  // ---- epilogue: add bias, plain store ----
#pragma unroll
  for (int reg = 0; reg < 4; ++reg) {
    int row = quad * 4 + reg;
    int dst = dstbase + row;
    int tt = ntyp[dst];
    const float* rb = rootb + (size_t)tt * CH;
#pragma unroll
    for (int ct = 0; ct < 8; ++ct) {
      int col = ct * 16 + m;
      out[(size_t)dst * CH + col] = acc[ct][reg] + rb[col];
    }
  }
}

extern "C" void kernel_launch(void* const* d_in, const int* in_sizes, int n_in,
                              void* d_out, int out_size, void* d_ws, size_t ws_size,
                              hipStream_t stream) {
  (void)in_sizes; (void)n_in; (void)out_size; (void)ws_size;
  const float* xsrc  = (const float*)d_in[0];
  const float* xt    = (const float*)d_in[1];
  const float* relw  = (const float*)d_in[2];
  const float* rootw = (const float*)d_in[3];
  const float* rootb = (const float*)d_in[4];
  const int* esrc = (const int*)d_in[5];
  const int* edst = (const int*)d_in[6];
  const int* etyp = (const int*)d_in[7];
  const int* ntyp = (const int*)d_in[8];
  float* out = (float*)d_out;

  char* ws = (char*)d_ws;
  int*   cnt    = (int*)(ws + CNT_O);
  int*   bsE    = (int*)(ws + BSE_O);
  int*   eoff   = (int*)(ws + EOFF_O);
  int*   cur    = (int*)(ws + CUR_O);
  int*   sedge  = (int*)(ws + SEDGE_O);
  ushort* wb    = (ushort*)(ws + WB_O);
  ushort* xb    = (ushort*)(ws + XB_O);
  ushort* xtb   = (ushort*)(ws + XTB_O);

  hipMemsetAsync(cnt, 0, (size_t)NP * 4, stream);
  k_count<<<dim3(COUNTB), dim3(256), 0, stream>>>(edst, etyp, cnt);
  k_s1<<<dim3(NB), dim3(256), 0, stream>>>(cnt, bsE);
  k_s23<<<dim3(NB), dim3(512), 0, stream>>>(cnt, bsE, eoff, cur);
  k_esconv<<<dim3(COUNTB + CONVB), dim3(256), 0, stream>>>(
      esrc, edst, etyp, cur, sedge, xsrc, xt, relw, rootw, xb, xtb, wb);
  k_mega<<<dim3(NBLK), dim3(64), 0, stream>>>(
      xb, xtb, wb, eoff, sedge, ntyp, rootb, out);
}

// Round 5
// 383.135 us; speedup vs baseline: 1.3530x; 1.0530x over previous
//
#include <hip/hip_runtime.h>

#define NSRC 100000
#define NTGT 50000
#define NE   600000
#define CH   128
#define NREL 7
#define NTYP 4
#define NP   (NREL * NTGT)          // 350000 (rel,dst) pairs
#define NB   ((NP + 1023) / 1024)   // scan blocks (342)
#define NBLK ((NTGT + 31) / 32)     // 1563 two-wave blocks, 16 dst rows per wave

typedef __attribute__((ext_vector_type(4))) float f32x4;
typedef __attribute__((ext_vector_type(8))) short bf16x8;
typedef unsigned int uint;
typedef unsigned short ushort;

static constexpr long long NXT4 = (long long)NTGT * CH / 4;     // xt -> xtb
static constexpr long long NWR4 = (long long)NREL * CH * CH / 4;
static constexpr long long NWT4 = (long long)NTYP * CH * CH / 4;
static constexpr int CONVB  = (int)((NXT4 + NWR4 + NWT4 + 255) / 256);
static constexpr int COUNTB = (NE + 255) / 256;
static constexpr int GATB   = NE / 16;   // 37500 blocks, 16 edges each

// ---- workspace layout ----
static constexpr size_t A256(size_t x) { return (x + 255) & ~(size_t)255; }
static constexpr size_t CNT_O   = 0;                                   // int[NP] (memset 0)
static constexpr size_t BSE_O   = A256(CNT_O + (size_t)NP * 4);        // int[NB]
static constexpr size_t EOFF_O  = A256(BSE_O + (size_t)NB * 4);        // int[NP+1]
static constexpr size_t CUR_O   = A256(EOFF_O + (size_t)(NP + 1) * 4); // int[NP]
static constexpr size_t WB_O    = A256(CUR_O + (size_t)NP * 4);        // bf16[11*CH*CH]
static constexpr size_t XTB_O   = A256(WB_O + (size_t)(NREL + NTYP) * CH * CH * 2);
static constexpr size_t MSG_O   = A256(XTB_O + (size_t)NTGT * CH * 2); // bf16[(NE+16)*CH]

#define GLOAD_LDS(gp, lp) __builtin_amdgcn_global_load_lds( \
    (const __attribute__((address_space(1))) void*)(gp), \
    (__attribute__((address_space(3))) void*)(lp), 16, 0, 0)
#define WAITVM4()   asm volatile("s_waitcnt vmcnt(4)" ::: "memory")
#define WAITVM0()   asm volatile("s_waitcnt vmcnt(0)" ::: "memory")
#define WAITLGKM0() asm volatile("s_waitcnt lgkmcnt(0)" ::: "memory")

__device__ __forceinline__ uint bfpack(float a, float b) {
  uint ua = __float_as_uint(a); ua = (ua + 0x7fff + ((ua >> 16) & 1)) >> 16;
  uint ub = __float_as_uint(b); ub = (ub + 0x7fff + ((ub >> 16) & 1)) >> 16;
  return ua | (ub << 16);
}
__device__ __forceinline__ ushort f2b(float x) {
  uint u = __float_as_uint(x);
  return (ushort)((u + 0x7fff + ((u >> 16) & 1)) >> 16);
}
__device__ __forceinline__ float bl(uint u) { return __uint_as_float(u << 16); }
__device__ __forceinline__ float bh(uint u) { return __uint_as_float(u & 0xffff0000u); }

// ---- fused: fp32->bf16 conversion (xt + weights only) + (rel,dst) counting ----
__global__ __launch_bounds__(256) void k_pre(
    const float* __restrict__ xt, const float* __restrict__ relw,
    const float* __restrict__ rootw, ushort* __restrict__ xtb,
    ushort* __restrict__ wb,
    const int* __restrict__ edst, const int* __restrict__ etyp,
    int* __restrict__ cnt) {
  int bx = blockIdx.x;
  if (bx < CONVB) {
    long long i4 = (long long)bx * 256 + threadIdx.x;
    const float* src; ushort* dst; long long off;
    if (i4 < NXT4) { src = xt; dst = xtb; off = i4; }
    else if (i4 < NXT4 + NWR4) { src = relw; dst = wb; off = i4 - NXT4; }
    else if (i4 < NXT4 + NWR4 + NWT4) {
      src = rootw; dst = wb + (size_t)NREL * CH * CH; off = i4 - NXT4 - NWR4;
    } else return;
    float4 v = *(const float4*)(src + off * 4);
    uint lo = (uint)f2b(v.x) | ((uint)f2b(v.y) << 16);
    uint hi = (uint)f2b(v.z) | ((uint)f2b(v.w) << 16);
    uint2 o = make_uint2(lo, hi);
    *(uint2*)(dst + off * 4) = o;
    return;
  }
  bx -= CONVB;
  int i = bx * 256 + threadIdx.x;
  if (i < NE) atomicAdd(&cnt[etyp[i] * NTGT + edst[i]], 1);
}

__global__ __launch_bounds__(256) void k_s1(const int* __restrict__ cnt,
                                            int* __restrict__ bsE) {
  __shared__ int sE[256];
  int t = threadIdx.x, p0 = blockIdx.x * 1024 + t * 4;
  int e = 0;
#pragma unroll
  for (int j = 0; j < 4; ++j) {
    int p = p0 + j;
    if (p < NP) e += cnt[p];
  }
  sE[t] = e; __syncthreads();
  for (int s = 128; s > 0; s >>= 1) {
    if (t < s) sE[t] += sE[t + s];
    __syncthreads();
  }
  if (t == 0) bsE[blockIdx.x] = sE[0];
}

// fused s2+s3: each block re-scans the 342 block sums, then scans its own chunk
__global__ __launch_bounds__(512) void k_s23(const int* __restrict__ cnt,
                                             const int* __restrict__ bsE,
                                             int* __restrict__ eoff,
                                             int* __restrict__ cur) {
  __shared__ int sE[512];
  __shared__ int sBase;
  int t = threadIdx.x;
  int e = (t < NB) ? bsE[t] : 0;
  sE[t] = e; __syncthreads();
  for (int s = 1; s < 512; s <<= 1) {
    int a = 0; if (t >= s) a = sE[t - s];
    __syncthreads();
    sE[t] += a;
    __syncthreads();
  }
  if (t == blockIdx.x) sBase = sE[t] - e;   // exclusive prefix for this block
  __syncthreads();
  int base0 = sBase;
  int p0 = blockIdx.x * 1024 + t * 2;
  int c0 = (p0 < NP) ? cnt[p0] : 0;
  int c1 = (p0 + 1 < NP) ? cnt[p0 + 1] : 0;
  int e2 = c0 + c1;
  sE[t] = e2; __syncthreads();
  for (int s = 1; s < 512; s <<= 1) {
    int a = 0; if (t >= s) a = sE[t - s];
    __syncthreads();
    sE[t] += a;
    __syncthreads();
  }
  int baseE = base0 + sE[t] - e2;
  if (p0 < NP)     { eoff[p0] = baseE;          cur[p0] = baseE; }
  if (p0 + 1 < NP) { eoff[p0 + 1] = baseE + c0; cur[p0 + 1] = baseE + c0; }
  if (p0 + 1 == NP - 1) eoff[NP] = baseE + c0 + c1;   // sentinel = NE
}

// ---- edge-parallel gather: materialize sorted bf16 messages ----
// 16 lanes per edge: broadcast-load triple, one atomic -> sorted slot,
// coalesced 512B fp32 row read, convert, coalesced 256B bf16 row write.
// Fully independent 2-level chains at max TLP (37.5k blocks).
__global__ __launch_bounds__(256) void k_gat(
    const float* __restrict__ xsrc, const int* __restrict__ esrc,
    const int* __restrict__ edst, const int* __restrict__ etyp,
    int* __restrict__ cur, ushort* __restrict__ msg) {
  int tid = threadIdx.x;
  int e = blockIdx.x * 16 + (tid >> 4);   // grid exact: NE/16 blocks
  int l16 = tid & 15;
  int src = esrc[e];                       // same addr across group -> broadcast
  int p = etyp[e] * NTGT + edst[e];
  int pos = 0;
  if (l16 == 0) pos = atomicAdd(&cur[p], 1);
  pos = __shfl(pos, (tid & 63) & ~15);     // leader lane of this 16-group
  const float* rp = xsrc + (size_t)src * CH + l16 * 8;
  float4 v0 = *(const float4*)rp;
  float4 v1 = *(const float4*)(rp + 4);
  uint4 o;
  o.x = bfpack(v0.x, v0.y); o.y = bfpack(v0.z, v0.w);
  o.z = bfpack(v1.x, v1.y); o.w = bfpack(v1.z, v1.w);
  *(uint4*)(msg + (size_t)pos * CH + l16 * 8) = o;
}

__device__ __forceinline__ void mfma_acc(const ushort* strip, const ushort* W,
                                         int m, int quad, f32x4* acc) {
  bf16x8 aF[4];
#pragma unroll
  for (int ks = 0; ks < 4; ++ks) {
    int c = ks * 4 + quad;
    aF[ks] = *(const bf16x8*)&strip[(m * 16 + (c ^ m)) << 3];
  }
#pragma unroll
  for (int ct = 0; ct < 8; ++ct) {
    int n = ct * 16 + m;
#pragma unroll
    for (int ks = 0; ks < 4; ++ks) {
      bf16x8 bF = *(const bf16x8*)(W + (size_t)n * CH + ks * 32 + quad * 8);
      acc[ct] = __builtin_amdgcn_mfma_f32_16x16x32_bf16(aF[ks], bF, acc[ct], 0, 0, 0);
    }
  }
}

// dst-major mega kernel: 16 dst rows per wave, 2 waves per block.
// Edge windows are contiguous in msg -> linear staging addresses:
// double-buffered global_load_lds with counted vmcnt(4) (never 0 mid-loop).
// All LDS wave-private; no __syncthreads.
__global__ __launch_bounds__(128) void k_mega(const ushort* __restrict__ msg,
    const ushort* __restrict__ xtb, const ushort* __restrict__ wb,
    const int* __restrict__ eoff, const int* __restrict__ ntyp,
    const float* __restrict__ rootb, float* __restrict__ out) {
  __shared__ ushort As[2 * 6144];       // 24 KB: per wave {buf0,buf1,strip} x 4KB
  int wv = threadIdx.x >> 6, ln = threadIdx.x & 63;
  ushort* Wbuf = As + wv * 6144;
  ushort* strip = Wbuf + 4096;
  int m = ln & 15, quad = ln >> 4;
  int dstbase = blockIdx.x * 32 + wv * 16;
  if (dstbase >= NTGT) return;          // safe: no block-wide syncs

  // prefetch: 7 relation offset windows (17 values each, lanes 0..16)
  int lc = min(ln, 16);
  int evr[NREL];
#pragma unroll
  for (int r = 0; r < NREL; ++r)
    evr[r] = eoff[r * NTGT + dstbase + lc];

  f32x4 acc[8];
#pragma unroll
  for (int ct = 0; ct < 8; ++ct) acc[ct] = (f32x4){0.f, 0.f, 0.f, 0.f};

#define STAGE(k) do { \
    const ushort* gp = msg + (size_t)(e0 + (k) * 16) * CH + (size_t)(ln * 8); \
    ushort* lb = Wbuf + ((k) & 1) * 2048; \
    GLOAD_LDS(gp, lb); \
    GLOAD_LDS(gp + 4 * CH, lb + 512); \
    GLOAD_LDS(gp + 8 * CH, lb + 1024); \
    GLOAD_LDS(gp + 12 * CH, lb + 1536); \
  } while (0)

  // ---- 7 relation phases ----
  for (int rel = 0; rel < NREL; ++rel) {
    int ev = evr[rel];
    int e0 = __builtin_amdgcn_readlane(ev, 0);
    int e1 = __builtin_amdgcn_readlane(ev, 16);
    if (e1 <= e0) continue;             // whole 16-row group empty for this rel

    float aRx[16], aRy[16];
#pragma unroll
    for (int i = 0; i < 16; ++i) { aRx[i] = 0.f; aRy[i] = 0.f; }

    int nchunk = (e1 - e0 + 15) >> 4;
    WAITLGKM0();                        // prior ds_reads of buf region drained
    STAGE(0);
    for (int k = 0; k < nchunk; ++k) {
      if (k + 1 < nchunk) { STAGE(k + 1); WAITVM4(); }
      else               { WAITVM0(); }
      const ushort* buf = Wbuf + (k & 1) * 2048;
      int cb = e0 + k * 16;
      int ce = cb + 16; if (ce > e1) ce = e1;
#pragma unroll
      for (int i = 0; i < 16; ++i) {
        int lo = __builtin_amdgcn_readlane(ev, i);
        int hi = __builtin_amdgcn_readlane(ev, i + 1);
        if (lo < cb) lo = cb;
        if (hi > ce) hi = ce;
        for (int e = lo; e < hi; ++e) {
          uint u = *(const uint*)&buf[((e - cb) << 7) + (ln << 1)];
          aRx[i] += bl(u);
          aRy[i] += bh(u);
        }
      }
    }

    // mean + bf16 pack -> swizzled strip (separate 4KB region, no alias)
#pragma unroll
    for (int i = 0; i < 16; ++i) {
      int n = __builtin_amdgcn_readlane(ev, i + 1) - __builtin_amdgcn_readlane(ev, i);
      float inv = (n > 0) ? __builtin_amdgcn_rcpf((float)n) : 0.f;
      uint w = bfpack(aRx[i] * inv, aRy[i] * inv);
      int c = ln >> 2;
      *(uint*)&strip[((i * 16 + (c ^ i)) << 3) + ((ln & 3) << 1)] = w;
    }
    mfma_acc(strip, wb + (size_t)rel * CH * CH, m, quad, acc);
  }
#undef STAGE

  // ---- 4 root-type phases (one-hot) ----
  int nv = ntyp[dstbase + min(ln, 15)];
  uint xr[16];
#pragma unroll
  for (int i = 0; i < 16; ++i)
    xr[i] = *(const uint*)(xtb + (size_t)(dstbase + i) * CH + (ln << 1));
#pragma unroll
  for (int ty = 0; ty < NTYP; ++ty) {
#pragma unroll
    for (int i = 0; i < 16; ++i) {
      int nti = __builtin_amdgcn_readlane(nv, i);
      uint w = (nti == ty) ? xr[i] : 0u;
      int c = ln >> 2;
      *(uint*)&strip[((i * 16 + (c ^ i)) << 3) + ((ln & 3) << 1)] = w;
    }
    mfma_acc(strip, wb + (size_t)(NREL + ty) * CH * CH, m, quad, acc);
  }

  // ---- epilogue: add bias, plain coalesced store ----
#pragma unroll
  for (int reg = 0; reg < 4; ++reg) {
    int row = quad * 4 + reg;
    int dst = dstbase + row;
    int tt = ntyp[dst];
    const float* rb = rootb + (size_t)tt * CH;
#pragma unroll
    for (int ct = 0; ct < 8; ++ct) {
      int col = ct * 16 + m;
      out[(size_t)dst * CH + col] = acc[ct][reg] + rb[col];
    }
  }
}

extern "C" void kernel_launch(void* const* d_in, const int* in_sizes, int n_in,
                              void* d_out, int out_size, void* d_ws, size_t ws_size,
                              hipStream_t stream) {
  (void)in_sizes; (void)n_in; (void)out_size; (void)ws_size;
  const float* xsrc  = (const float*)d_in[0];
  const float* xt    = (const float*)d_in[1];
  const float* relw  = (const float*)d_in[2];
  const float* rootw = (const float*)d_in[3];
  const float* rootb = (const float*)d_in[4];
  const int* esrc = (const int*)d_in[5];
  const int* edst = (const int*)d_in[6];
  const int* etyp = (const int*)d_in[7];
  const int* ntyp = (const int*)d_in[8];
  float* out = (float*)d_out;

  char* ws = (char*)d_ws;
  int*   cnt    = (int*)(ws + CNT_O);
  int*   bsE    = (int*)(ws + BSE_O);
  int*   eoff   = (int*)(ws + EOFF_O);
  int*   cur    = (int*)(ws + CUR_O);
  ushort* wb    = (ushort*)(ws + WB_O);
  ushort* xtb   = (ushort*)(ws + XTB_O);
  ushort* msg   = (ushort*)(ws + MSG_O);

  hipMemsetAsync(cnt, 0, (size_t)NP * 4, stream);
  k_pre<<<dim3(CONVB + COUNTB), dim3(256), 0, stream>>>(
      xt, relw, rootw, xtb, wb, edst, etyp, cnt);
  k_s1<<<dim3(NB), dim3(256), 0, stream>>>(cnt, bsE);
  k_s23<<<dim3(NB), dim3(512), 0, stream>>>(cnt, bsE, eoff, cur);
  k_gat<<<dim3(GATB), dim3(256), 0, stream>>>(xsrc, esrc, edst, etyp, cur, msg);
  k_mega<<<dim3(NBLK), dim3(128), 0, stream>>>(
      msg, xtb, wb, eoff, ntyp, rootb, out);
}

// Round 6
// 381.112 us; speedup vs baseline: 1.3602x; 1.0053x over previous
//
#include <hip/hip_runtime.h>

#define NSRC 100000
#define NTGT 50000
#define NE   600000
#define CH   128
#define NREL 7
#define NTYP 4
#define NP   (NREL * NTGT)          // 350000 (rel,dst) pairs
#define NB   ((NP + 1023) / 1024)   // scan blocks (342)
#define NBLK (NTGT / 16)            // 3125 one-wave blocks, 16 dst rows each

typedef __attribute__((ext_vector_type(4))) float f32x4;
typedef __attribute__((ext_vector_type(8))) short bf16x8;
typedef unsigned int uint;
typedef unsigned short ushort;

static constexpr long long NXB4 = (long long)NSRC * CH / 4;
static constexpr long long NXT4 = (long long)NTGT * CH / 4;
static constexpr long long NWR4 = (long long)NREL * CH * CH / 4;
static constexpr long long NWT4 = (long long)NTYP * CH * CH / 4;
static constexpr int CONVB  = (int)((NXB4 + NXT4 + NWR4 + NWT4 + 255) / 256);
static constexpr int COUNTB = (NE + 255) / 256;
static constexpr int GATB   = NE / 16;   // 37500 blocks, 16 edges each

// ---- k_mega LDS layout (bytes) ----
// strip: 4096 | buf0: 8320 (8 groups x 1040: 1024 data + 16 pad) | buf1: 8320
// desc: 2048 (512 chunk descriptors)
#define STRIP_OFF 0
#define BUF0_OFF  4096
#define BUFSZB    8320
#define DESC_OFF  (4096 + 2 * 8320)
#define LDS_TOT   (DESC_OFF + 2048)

// ---- workspace layout ----
static constexpr size_t A256(size_t x) { return (x + 255) & ~(size_t)255; }
static constexpr size_t CNT_O   = 0;                                   // int[NP] (memset 0)
static constexpr size_t BSE_O   = A256(CNT_O + (size_t)NP * 4);        // int[NB]
static constexpr size_t EOFF_O  = A256(BSE_O + (size_t)NB * 4);        // int[NP+1]
static constexpr size_t CUR_O   = A256(EOFF_O + (size_t)(NP + 1) * 4); // int[NP]
static constexpr size_t WB_O    = A256(CUR_O + (size_t)NP * 4);        // bf16[11*CH*CH]
static constexpr size_t XB_O    = A256(WB_O + (size_t)(NREL + NTYP) * CH * CH * 2);
static constexpr size_t XTB_O   = A256(XB_O + (size_t)NSRC * CH * 2);  // bf16[NTGT*CH]
static constexpr size_t MSG_O   = A256(XTB_O + (size_t)NTGT * CH * 2); // bf16[(NE+32)*CH]

#define GLOAD_LDS(gp, lp) __builtin_amdgcn_global_load_lds( \
    (const __attribute__((address_space(1))) void*)(gp), \
    (__attribute__((address_space(3))) void*)(lp), 16, 0, 0)
#define WAITVM8()   asm volatile("s_waitcnt vmcnt(8)" ::: "memory")
#define WAITVM0()   asm volatile("s_waitcnt vmcnt(0)" ::: "memory")
#define WAITLGKM0() asm volatile("s_waitcnt lgkmcnt(0)" ::: "memory")
#define SB0()       __builtin_amdgcn_sched_barrier(0)

__device__ __forceinline__ ushort f2b(float x) {
  uint u = __float_as_uint(x);
  return (ushort)((u + 0x7fff + ((u >> 16) & 1)) >> 16);
}

// ---- fused: fp32->bf16 conversion (xsrc + xt + weights) + (rel,dst) counting ----
__global__ __launch_bounds__(256) void k_pre(
    const float* __restrict__ xsrc, const float* __restrict__ xt,
    const float* __restrict__ relw, const float* __restrict__ rootw,
    ushort* __restrict__ xb, ushort* __restrict__ xtb, ushort* __restrict__ wb,
    const int* __restrict__ edst, const int* __restrict__ etyp,
    int* __restrict__ cnt) {
  int bx = blockIdx.x;
  if (bx < CONVB) {
    long long i4 = (long long)bx * 256 + threadIdx.x;
    const float* src; ushort* dst; long long off;
    if (i4 < NXB4) { src = xsrc; dst = xb; off = i4; }
    else if (i4 < NXB4 + NXT4) { src = xt; dst = xtb; off = i4 - NXB4; }
    else if (i4 < NXB4 + NXT4 + NWR4) { src = relw; dst = wb; off = i4 - NXB4 - NXT4; }
    else if (i4 < NXB4 + NXT4 + NWR4 + NWT4) {
      src = rootw; dst = wb + (size_t)NREL * CH * CH; off = i4 - NXB4 - NXT4 - NWR4;
    } else return;
    float4 v = *(const float4*)(src + off * 4);
    uint lo = (uint)f2b(v.x) | ((uint)f2b(v.y) << 16);
    uint hi = (uint)f2b(v.z) | ((uint)f2b(v.w) << 16);
    uint2 o = make_uint2(lo, hi);
    *(uint2*)(dst + off * 4) = o;
    return;
  }
  bx -= CONVB;
  int i = bx * 256 + threadIdx.x;
  if (i < NE) atomicAdd(&cnt[etyp[i] * NTGT + edst[i]], 1);
}

__global__ __launch_bounds__(256) void k_s1(const int* __restrict__ cnt,
                                            int* __restrict__ bsE) {
  __shared__ int sE[256];
  int t = threadIdx.x, p0 = blockIdx.x * 1024 + t * 4;
  int e = 0;
#pragma unroll
  for (int j = 0; j < 4; ++j) {
    int p = p0 + j;
    if (p < NP) e += cnt[p];
  }
  sE[t] = e; __syncthreads();
  for (int s = 128; s > 0; s >>= 1) {
    if (t < s) sE[t] += sE[t + s];
    __syncthreads();
  }
  if (t == 0) bsE[blockIdx.x] = sE[0];
}

// fused s2+s3: each block re-scans the 342 block sums, then scans its own chunk
__global__ __launch_bounds__(512) void k_s23(const int* __restrict__ cnt,
                                             const int* __restrict__ bsE,
                                             int* __restrict__ eoff,
                                             int* __restrict__ cur) {
  __shared__ int sE[512];
  __shared__ int sBase;
  int t = threadIdx.x;
  int e = (t < NB) ? bsE[t] : 0;
  sE[t] = e; __syncthreads();
  for (int s = 1; s < 512; s <<= 1) {
    int a = 0; if (t >= s) a = sE[t - s];
    __syncthreads();
    sE[t] += a;
    __syncthreads();
  }
  if (t == blockIdx.x) sBase = sE[t] - e;   // exclusive prefix for this block
  __syncthreads();
  int base0 = sBase;
  int p0 = blockIdx.x * 1024 + t * 2;
  int c0 = (p0 < NP) ? cnt[p0] : 0;
  int c1 = (p0 + 1 < NP) ? cnt[p0 + 1] : 0;
  int e2 = c0 + c1;
  sE[t] = e2; __syncthreads();
  for (int s = 1; s < 512; s <<= 1) {
    int a = 0; if (t >= s) a = sE[t - s];
    __syncthreads();
    sE[t] += a;
    __syncthreads();
  }
  int baseE = base0 + sE[t] - e2;
  if (p0 < NP)     { eoff[p0] = baseE;          cur[p0] = baseE; }
  if (p0 + 1 < NP) { eoff[p0 + 1] = baseE + c0; cur[p0 + 1] = baseE + c0; }
  if (p0 + 1 == NP - 1) eoff[NP] = baseE + c0 + c1;   // sentinel = NE
}

// ---- edge-parallel gather: materialize sorted bf16 messages (pure copy) ----
__global__ __launch_bounds__(256) void k_gat(
    const ushort* __restrict__ xb, const int* __restrict__ esrc,
    const int* __restrict__ edst, const int* __restrict__ etyp,
    int* __restrict__ cur, ushort* __restrict__ msg) {
  int tid = threadIdx.x;
  int e = blockIdx.x * 16 + (tid >> 4);   // grid exact: NE/16 blocks
  int l16 = tid & 15;
  int src = esrc[e];                       // same addr across group -> broadcast
  int p = etyp[e] * NTGT + edst[e];
  int pos = 0;
  if (l16 == 0) pos = atomicAdd(&cur[p], 1);
  pos = __shfl(pos, (tid & 63) & ~15);     // leader lane of this 16-group
  uint4 v = *(const uint4*)(xb + (size_t)src * CH + (l16 << 3));
  *(uint4*)(msg + (size_t)pos * CH + (l16 << 3)) = v;
}

// weight GEMM tail: A from swizzled LDS strip, B from global weights
__device__ __forceinline__ void mfma_acc(const ushort* strip, const ushort* W,
                                         int m, int quad, f32x4* acc) {
  bf16x8 aF[4];
#pragma unroll
  for (int ks = 0; ks < 4; ++ks) {
    int c = ks * 4 + quad;
    aF[ks] = *(const bf16x8*)&strip[(m * 16 + (c ^ m)) << 3];
  }
#pragma unroll
  for (int ct = 0; ct < 8; ++ct) {
    int n = ct * 16 + m;
#pragma unroll
    for (int ks = 0; ks < 4; ++ks) {
      bf16x8 bF = *(const bf16x8*)(W + (size_t)n * CH + ks * 32 + quad * 8);
      acc[ct] = __builtin_amdgcn_mfma_f32_16x16x32_bf16(aF[ks], bF, acc[ct], 0, 0, 0);
    }
  }
}

// One-wave mega kernel: 16 dst rows per block.
//  - Flat cross-relation chunk stream (32 edges/chunk) staged by global_load_lds
//    into 2 LDS buffers, counted vmcnt(8), descriptors in LDS.
//  - Consume = indicator-MFMA segment sum: A = 0/1 row-membership matrix built
//    in registers (no memory), B = staged chunk via independent ds_read_u16
//    (conflict-free with 16B/KB pad). No dependent LDS chains, no row loops.
//  - Mean via rcp post-MFMA -> bf16 strip -> weight GEMM (unchanged tail).
__global__ __launch_bounds__(64) void k_mega(const ushort* __restrict__ msg,
    const ushort* __restrict__ xtb, const ushort* __restrict__ wb,
    const int* __restrict__ eoff, const int* __restrict__ ntyp,
    const float* __restrict__ rootb, float* __restrict__ out) {
  __shared__ char As[LDS_TOT];
  ushort* strip = (ushort*)(As + STRIP_OFF);
  int* descp = (int*)(As + DESC_OFF);
  int ln = threadIdx.x;
  int m = ln & 15, quad = ln >> 4;
  int dstbase = blockIdx.x * 16;

  // prefetch: 7 relation offset windows (17 values each, lanes 0..16)
  int lc = min(ln, 16);
  int evr[NREL];
#pragma unroll
  for (int r = 0; r < NREL; ++r)
    evr[r] = eoff[r * NTGT + dstbase + lc];

  // wave-uniform per-relation bounds + chunk counts; build descriptor list
  int e0s[NREL], e1s[NREL], crs[NREL];
  int C = 0;
#pragma unroll
  for (int r = 0; r < NREL; ++r) {
    e0s[r] = __builtin_amdgcn_readlane(evr[r], 0);
    e1s[r] = __builtin_amdgcn_readlane(evr[r], 16);
    crs[r] = (e1s[r] - e0s[r] + 31) >> 5;
  }
#pragma unroll
  for (int r = 0; r < NREL; ++r) {
    for (int c = 0; c < crs[r]; ++c) {
      if (ln == 0) descp[C + c] = e0s[r] + c * 32;
    }
    C += crs[r];
  }

  f32x4 acc[8];
#pragma unroll
  for (int ct = 0; ct < 8; ++ct) acc[ct] = (f32x4){0.f, 0.f, 0.f, 0.f};

#define STAGE(bufoff, estart) do { \
    _Pragma("unroll") \
    for (int g = 0; g < 8; ++g) { \
      const ushort* gp = msg + (size_t)((estart) + g * 4 + quad) * CH + (m << 3); \
      GLOAD_LDS(gp, As + (bufoff) + g * 1040); \
    } } while (0)

  int tstg = 0, tcons = 0;
  if (C > 0) {            // prologue: stage chunk 0
    int d0 = descp[0];
    WAITLGKM0();          // desc visible
    SB0();
    STAGE(BUF0_OFF, d0);
    tstg = 1;
  }

  // ---- 7 relation phases ----
#pragma unroll
  for (int rel = 0; rel < NREL; ++rel) {
    if (crs[rel] == 0) continue;          // uniform; zero contribution
    int lo_m = __shfl(evr[rel], m);
    int hi_m = __shfl(evr[rel], m + 1);

    f32x4 seg[8];
#pragma unroll
    for (int ct = 0; ct < 8; ++ct) seg[ct] = (f32x4){0.f, 0.f, 0.f, 0.f};

    for (int c = 0; c < crs[rel]; ++c) {
      // stage ahead one chunk
      if (tstg < C) {
        int nd = descp[tstg];
        WAITLGKM0();                      // nd ready; prior buffer reads drained
        SB0();
        STAGE(BUF0_OFF + (tstg & 1) * BUFSZB, nd);
        ++tstg;
      }
      // wait for chunk tcons's 8 loads (counted, never drains the prefetch)
      if (tstg > tcons + 1) { WAITVM8(); } else { WAITVM0(); }
      SB0();
      const char* buf = As + BUF0_OFF + (tcons & 1) * BUFSZB;
      int cb = e0s[rel] + c * 32;
      int k0 = lo_m - cb, k1 = hi_m - cb;

      // A = row-membership indicator (bf16 1.0/0.0), built in registers
      union { uint u[4]; bf16x8 v; } Afr;
      int kq = quad * 8;
#pragma unroll
      for (int p2 = 0; p2 < 4; ++p2) {
        int kk = kq + p2 * 2;
        uint lo = (kk >= k0 && kk < k1) ? 0x3f80u : 0u;
        uint hi = (kk + 1 >= k0 && kk + 1 < k1) ? 0x3f800000u : 0u;
        Afr.u[p2] = lo | hi;
      }
      // B = staged chunk, 8 independent u16 reads per ct (conflict-free w/ pad)
#pragma unroll
      for (int ct = 0; ct < 8; ++ct) {
        union { ushort s[8]; bf16x8 v; } Bfr;
#pragma unroll
        for (int j = 0; j < 8; ++j) {
          int e = kq + j;
          Bfr.s[j] = *(const ushort*)(buf + e * 256 + ((e >> 2) << 4) +
                                      ((ct * 16 + m) << 1));
        }
        seg[ct] = __builtin_amdgcn_mfma_f32_16x16x32_bf16(Afr.v, Bfr.v, seg[ct], 0, 0, 0);
      }
      ++tcons;
    }

    // mean + bf16 pack -> swizzled strip (seg C-layout: row=quad*4+reg, col=m)
#pragma unroll
    for (int reg = 0; reg < 4; ++reg) {
      int row = quad * 4 + reg;
      int lo = __shfl(evr[rel], row);
      int hi = __shfl(evr[rel], row + 1);
      float inv = (hi > lo) ? __builtin_amdgcn_rcpf((float)(hi - lo)) : 0.f;
#pragma unroll
      for (int ct = 0; ct < 8; ++ct) {
        int ch = ct * 16 + m;
        int cblk = ch >> 3;
        strip[((row * 16 + (cblk ^ row)) << 3) + (ch & 7)] = f2b(seg[ct][reg] * inv);
      }
    }
    WAITLGKM0();                          // strip writes visible before A-reads
    SB0();
    mfma_acc(strip, wb + (size_t)rel * CH * CH, m, quad, acc);
  }
#undef STAGE

  // ---- 4 root-type phases (one-hot) ----
  int nv = ntyp[dstbase + min(ln, 15)];
  uint xr[16];
#pragma unroll
  for (int i = 0; i < 16; ++i)
    xr[i] = *(const uint*)(xtb + (size_t)(dstbase + i) * CH + (ln << 1));
#pragma unroll
  for (int ty = 0; ty < NTYP; ++ty) {
#pragma unroll
    for (int i = 0; i < 16; ++i) {
      int nti = __builtin_amdgcn_readlane(nv, i);
      uint w = (nti == ty) ? xr[i] : 0u;
      int cb2 = ln >> 2;
      *(uint*)&strip[((i * 16 + (cb2 ^ i)) << 3) + ((ln & 3) << 1)] = w;
    }
    WAITLGKM0();
    SB0();
    mfma_acc(strip, wb + (size_t)(NREL + ty) * CH * CH, m, quad, acc);
  }

  // ---- epilogue: add bias, plain coalesced store ----
#pragma unroll
  for (int reg = 0; reg < 4; ++reg) {
    int row = quad * 4 + reg;
    int dst = dstbase + row;
    int tt = ntyp[dst];
    const float* rb = rootb + (size_t)tt * CH;
#pragma unroll
    for (int ct = 0; ct < 8; ++ct) {
      int col = ct * 16 + m;
      out[(size_t)dst * CH + col] = acc[ct][reg] + rb[col];
    }
  }
}

extern "C" void kernel_launch(void* const* d_in, const int* in_sizes, int n_in,
                              void* d_out, int out_size, void* d_ws, size_t ws_size,
                              hipStream_t stream) {
  (void)in_sizes; (void)n_in; (void)out_size; (void)ws_size;
  const float* xsrc  = (const float*)d_in[0];
  const float* xt    = (const float*)d_in[1];
  const float* relw  = (const float*)d_in[2];
  const float* rootw = (const float*)d_in[3];
  const float* rootb = (const float*)d_in[4];
  const int* esrc = (const int*)d_in[5];
  const int* edst = (const int*)d_in[6];
  const int* etyp = (const int*)d_in[7];
  const int* ntyp = (const int*)d_in[8];
  float* out = (float*)d_out;

  char* ws = (char*)d_ws;
  int*   cnt    = (int*)(ws + CNT_O);
  int*   bsE    = (int*)(ws + BSE_O);
  int*   eoff   = (int*)(ws + EOFF_O);
  int*   cur    = (int*)(ws + CUR_O);
  ushort* wb    = (ushort*)(ws + WB_O);
  ushort* xb    = (ushort*)(ws + XB_O);
  ushort* xtb   = (ushort*)(ws + XTB_O);
  ushort* msg   = (ushort*)(ws + MSG_O);

  hipMemsetAsync(cnt, 0, (size_t)NP * 4, stream);
  // zero the 32-row staging slack past msg[NE] (full-chunk stages may touch it)
  hipMemsetAsync(msg + (size_t)NE * CH, 0, (size_t)32 * CH * 2, stream);
  k_pre<<<dim3(CONVB + COUNTB), dim3(256), 0, stream>>>(
      xsrc, xt, relw, rootw, xb, xtb, wb, edst, etyp, cnt);
  k_s1<<<dim3(NB), dim3(256), 0, stream>>>(cnt, bsE);
  k_s23<<<dim3(NB), dim3(512), 0, stream>>>(cnt, bsE, eoff, cur);
  k_gat<<<dim3(GATB), dim3(256), 0, stream>>>(xb, esrc, edst, etyp, cur, msg);
  k_mega<<<dim3(NBLK), dim3(64), 0, stream>>>(
      msg, xtb, wb, eoff, ntyp, rootb, out);
}